// Round 8
// baseline (2530.065 us; speedup 1.0000x reference)
//
#include <hip/hip_runtime.h>
#include <hip/hip_bf16.h>
#include <cstdint>

#define B_ 8
#define LABEL_NC 19
#define H_ 128
#define W_ 128
#define UC 640
#define EPS_ 1e-5f

typedef __attribute__((ext_vector_type(8))) short s8v;    // 8 bf16 (4 VGPR) MFMA frag
typedef __attribute__((ext_vector_type(4))) float f4v;    // MFMA acc
typedef __attribute__((ext_vector_type(4))) int i4v;      // 16B ld/st
typedef unsigned short ushort_t;

__device__ __forceinline__ ushort_t f2b(float f) {
    union { float f; uint32_t u; } a; a.f = f;
    uint32_t u = a.u;
    return (ushort_t)((u + 0x7FFFu + ((u >> 16) & 1u)) >> 16);  // RNE
}

__device__ __forceinline__ void gl2lds16(const ushort_t* g, ushort_t* l) {
    __builtin_amdgcn_global_load_lds(
        (const __attribute__((address_space(1))) unsigned int*)g,
        (__attribute__((address_space(3))) unsigned int*)l, 16, 0, 0);
}

// ---------------- kernel 0: fold blend weights into combined conv weights ----------------
__global__ void __launch_bounds__(256) k_prep(
    const float* __restrict__ w_gamma, const float* __restrict__ w_beta,
    const float* __restrict__ w_sgamma, const float* __restrict__ w_sbeta,
    const float* __restrict__ b_gamma, const float* __restrict__ b_beta,
    const float* __restrict__ b_sgamma, const float* __restrict__ b_sbeta,
    const float* __restrict__ alpha_beta, const float* __restrict__ alpha_gamma,
    ushort_t* __restrict__ Wt, float* __restrict__ bias_s, float* __restrict__ bias_o,
    float* __restrict__ zpage)
{
    float wb = 1.f / (1.f + __expf(-alpha_beta[0]));
    float wg = 1.f / (1.f + __expf(-alpha_gamma[0]));
    int gid = blockIdx.x * 256 + threadIdx.x;
    if (gid < 256) bias_s[gid] = wg * b_sgamma[gid] + (1.f - wg) * b_gamma[gid];
    else if (gid < 512) bias_o[gid - 256] = wb * b_sbeta[gid - 256] + (1.f - wb) * b_beta[gid - 256];
    if (gid < 8192) zpage[gid] = 0.f;   // 32KB zero page

    const int total = 9 * 512 * 640;
    for (int idx = gid; idx < total; idx += gridDim.x * 256) {
        int tap = idx / (512 * 640);
        int r = idx - tap * (512 * 640);
        int co = r / 640, ci = r - co * 640;
        int kh = tap / 3, kw = tap - kh * 3;
        float v;
        if (co < 256) {
            if (ci < 128) v = (1.f - wg) * w_gamma[((co * 128 + ci) * 3 + kh) * 3 + kw];
            else          v = wg * w_sgamma[((co * 512 + (ci - 128)) * 3 + kh) * 3 + kw];
        } else {
            int c2 = co - 256;
            if (ci < 128) v = (1.f - wb) * w_beta[((c2 * 128 + ci) * 3 + kh) * 3 + kw];
            else          v = wb * w_sbeta[((c2 * 512 + (ci - 128)) * 3 + kh) * 3 + kw];
        }
        Wt[idx] = f2b(v);
    }
}

// ---------------- kernel 1: per-(b,c) instance-norm stats ----------------
__global__ void __launch_bounds__(256) k_stats(const float* __restrict__ x,
                                               float* __restrict__ mean, float* __restrict__ rstd)
{
    int bc = blockIdx.x;  // b*256+c
    const float4* p = (const float4*)(x + (size_t)bc * (H_ * W_));
    float s = 0.f, s2 = 0.f;
    for (int i = threadIdx.x; i < H_ * W_ / 4; i += 256) {
        float4 v = p[i];
        s += v.x + v.y + v.z + v.w;
        s2 += v.x * v.x + v.y * v.y + v.z * v.z + v.w * v.w;
    }
    #pragma unroll
    for (int o = 32; o > 0; o >>= 1) { s += __shfl_xor(s, o); s2 += __shfl_xor(s2, o); }
    __shared__ float red[8];
    int wave = threadIdx.x >> 6, lane = threadIdx.x & 63;
    if (lane == 0) { red[wave] = s; red[wave + 4] = s2; }
    __syncthreads();
    if (threadIdx.x == 0) {
        float ts = red[0] + red[1] + red[2] + red[3];
        float t2 = red[4] + red[5] + red[6] + red[7];
        float m = ts * (1.f / 16384.f);
        float v = t2 * (1.f / 16384.f) - m * m;
        mean[bc] = m;
        rstd[bc] = rsqrtf(v + EPS_);
    }
}

// ---------------- kernel 2: build U[b][h][w][640] bf16 (NHWC) ----------------
__global__ void __launch_bounds__(256) k_buildU(
    const float* __restrict__ segmap, const float* __restrict__ style,
    const float* __restrict__ w_shared, const float* __restrict__ b_shared,
    ushort_t* __restrict__ U)
{
    int bh = blockIdx.x;
    int b = bh >> 7, h = bh & 127;
    __shared__ float seg[3][LABEL_NC][W_];   // rows h-1,h,h+1
    const float* segb = segmap + (size_t)b * (LABEL_NC * H_ * W_);
    for (int idx = threadIdx.x; idx < 3 * LABEL_NC * W_; idx += 256) {
        int w = idx & 127;
        int l = (idx >> 7) % LABEL_NC;
        int rr = idx / (LABEL_NC * W_);
        int hh = h + rr - 1;
        seg[rr][l][w] = (hh >= 0 && hh < H_) ? segb[((size_t)l * H_ + hh) * W_ + w] : 0.f;
    }
    __syncthreads();

    int t = threadIdx.x;
    int w = t & 127;
    int grp = __builtin_amdgcn_readfirstlane(t >> 7);   // 0 or 1, wave-uniform
    ushort_t* Urow = U + (((size_t)(b * H_ + h)) * W_ + w) * UC;

    for (int cb = 0; cb < 4; ++cb) {
        int co0 = grp * 64 + cb * 16;
        float acc[16];
        #pragma unroll
        for (int i = 0; i < 16; ++i) acc[i] = b_shared[co0 + i];
        for (int l = 0; l < LABEL_NC; ++l) {
            #pragma unroll
            for (int kh = 0; kh < 3; ++kh) {
                float sm = (w > 0)   ? seg[kh][l][w - 1] : 0.f;
                float s0 = seg[kh][l][w];
                float sp = (w < 127) ? seg[kh][l][w + 1] : 0.f;
                const float* wp = w_shared + ((size_t)co0 * LABEL_NC + l) * 9 + kh * 3;
                #pragma unroll
                for (int i = 0; i < 16; ++i) {
                    const float* wpi = wp + i * (LABEL_NC * 9);
                    acc[i] += sm * wpi[0] + s0 * wpi[1] + sp * wpi[2];
                }
            }
        }
        #pragma unroll
        for (int i = 0; i < 16; ++i)
            Urow[co0 + i] = f2b(acc[i] > 0.f ? acc[i] : 0.f);
    }

    float segr[LABEL_NC];
    #pragma unroll
    for (int l = 0; l < LABEL_NC; ++l) segr[l] = seg[1][l][w];
    const float* styb = style + (size_t)b * (LABEL_NC * 512);
    for (int sb = 0; sb < 16; ++sb) {
        int s0 = grp * 256 + sb * 16;
        float acc[16];
        #pragma unroll
        for (int i = 0; i < 16; ++i) acc[i] = 0.f;
        for (int l = 0; l < LABEL_NC; ++l) {
            const float* sp = styb + l * 512 + s0;
            float sl = segr[l];
            #pragma unroll
            for (int i = 0; i < 16; ++i) acc[i] += sl * sp[i];
        }
        #pragma unroll
        for (int i = 0; i < 16; ++i) Urow[128 + s0 + i] = f2b(acc[i]);
    }
}

// ---------------- kernel 3: main implicit-GEMM conv + fused epilogue ----------------
// 512 threads (8 waves, 4wm x 2wn). M = 256 px (2 rows), N = 256 (128 scale + 128 offset).
// BK=32, per-tap barrier (180 bodies), B staged 3-deep into 3 slots (stage B(t+3) at t;
// B(t)'s slot is frag-consumed at t-1 so overwrite is safe), A staged at tap 5.
// FRAGMENT PING-PONG: at tap t issue the 12 ds_reads for tap t+1's fragments, then run
// tap t's MFMAs -- no dependence, scheduler interleaves, LDS-read pipe overlaps MFMA pipe.
// Counted vmcnt (derived): steady 2; taps 6,7 -> 6; tap8 -> 2 (covers A'+B(0')); lastch
// winds down 2/0/0. lgkmcnt(0) before each barrier guards ds_read vs gl2lds overwrite.
// LDS slot swizzle: phys_slot = data_slot ^ ((row>>1)&3).
#define BK 32

#define READ_FRAGS(AF, BF, DHP1, DW, SBB, SAB) { \
    _Pragma("unroll") \
    for (int mi = 0; mi < 4; ++mi) { \
        int p_ = wm * 64 + mi * 16 + (ln & 15); \
        int q_ = (p_ & 127) + (DW); \
        int qc_ = q_ < 0 ? 0 : (q_ > 127 ? 127 : q_); \
        int r_ = (p_ >> 7) + (DHP1); \
        s8v v_ = *(const s8v*)&(SAB)[(size_t)(((r_ * 128 + qc_) << 2) + (sd ^ ((qc_ >> 1) & 3))) * 8]; \
        if ((DW) != 0 && (q_ < 0 || q_ > 127)) { s8v z_ = {}; v_ = z_; } \
        AF[mi] = v_; \
    } \
    _Pragma("unroll") \
    for (int ni = 0; ni < 8; ++ni) { \
        int c_ = wn * 128 + (ni >> 2) * 64 + (ni & 3) * 16 + (ln & 15); \
        BF[ni] = *(const s8v*)&(SBB)[(size_t)((c_ << 2) + (sd ^ ((c_ >> 1) & 3))) * 8]; \
    } }

#define MFMA_SET(AF, BF) { \
    __builtin_amdgcn_s_setprio(1); \
    _Pragma("unroll") \
    for (int mi = 0; mi < 4; ++mi) \
        _Pragma("unroll") \
        for (int ni = 0; ni < 8; ++ni) \
            acc[mi][ni] = __builtin_amdgcn_mfma_f32_16x16x32_bf16(AF[mi], BF[ni], acc[mi][ni], 0, 0, 0); \
    __builtin_amdgcn_s_setprio(0); }

__global__ void __launch_bounds__(512, 1) k_conv(
    const ushort_t* __restrict__ U, const ushort_t* __restrict__ Wt,
    const ushort_t* __restrict__ zp,
    const float* __restrict__ x, const float* __restrict__ mean, const float* __restrict__ rstd,
    const float* __restrict__ bias_s, const float* __restrict__ bias_o,
    float* __restrict__ out)
{
    // bijective XCD-chunk swizzle (nwg=1024, 128 per XCD)
    int orig = blockIdx.x;
    int wg = (orig & 7) * 128 + (orig >> 3);
    int mtile = wg >> 1;
    int cohalf = wg & 1;
    int b = mtile >> 6;
    int h0 = (mtile & 63) << 1;

    extern __shared__ ushort_t smem[];
    // smem + ab*16384        : sA[2]  (each 4 rows x 128 px x 32 ci = 32KB)
    // smem + 32768 + bi*8192 : sB[3]  (each 256 ch x 32 ci = 16KB)

    int t = threadIdx.x;
    int wv = t >> 6, ln = t & 63;
    int wm = wv >> 1, wn = wv & 1;
    int sd = ln >> 4;                 // 16B k-slot

    const ushort_t* Ub = U + (size_t)b * (H_ * W_ * UC);

    f4v acc[4][8] = {};   // [mi][ni]; ni<4 scale, ni>=4 offset (same channels)
    s8v afA[4], bfA[8], afB[4], bfB[8];   // ping-pong fragment sets

    auto stage_A = [&](int ci0, int ab) {      // 4 loads/thread -> 32KB
        ushort_t* sAb = smem + ab * 16384;
        #pragma unroll
        for (int i = 0; i < 4; ++i) {
            int issue = wv * 4 + i;            // 32 issues of 1KB
            int hh = h0 - 1 + (issue >> 3);    // wave-uniform row
            int w = issue * 16 + (ln >> 2);
            int sl = (ln & 3) ^ ((w >> 1) & 3);    // inverse-swizzled source slot
            const ushort_t* src = (hh >= 0 && hh < H_)
                ? Ub + ((size_t)hh * W_ + (w & 127)) * UC + ci0 + (sl << 3)
                : zp + (size_t)ln * 8;
            gl2lds16(src, sAb + (size_t)issue * 512);
        }
    };
    auto stage_B = [&](int tapX, int ci0X, int bi) {   // 2 loads/thread -> 16KB
        ushort_t* base = smem + 32768 + bi * 8192;
        #pragma unroll
        for (int j = 0; j < 2; ++j) {
            int issue = wv * 2 + j;            // 16 issues of 1KB
            int c = issue * 16 + (ln >> 2);    // LDS row (0..255)
            int sl = (ln & 3) ^ ((c >> 1) & 3);
            int gq = (c >> 6) & 1;
            int cbase = ((c >> 7) << 6) + (c & 63);
            int co = gq * 256 + cohalf * 128 + cbase;
            const ushort_t* src = Wt + ((size_t)tapX * 512 + co) * UC + ci0X + (sl << 3);
            gl2lds16(src, base + (size_t)issue * 512);
        }
    };

    // ---- prologue: A(ch0), B(0), B(1); frags(0) -> set A ----
    stage_A(0, 0);
    stage_B(0, 0, 0);
    stage_B(1, 0, 1);
    asm volatile("s_waitcnt vmcnt(2)" ::: "memory");   // A + B(0) landed
    __builtin_amdgcn_s_barrier();
    READ_FRAGS(afA, bfA, 0, -1, (smem + 32768), smem);

    for (int chp = 0; chp < 10; ++chp) {
        #pragma unroll
        for (int half = 0; half < 2; ++half) {
            int ch = chp * 2 + half;
            int ci0 = ch * BK;
            bool lastch = (ch == 19);
            bool firstch = (ch == 0);
            ushort_t* sAb = smem + (ch & 1) * 16384;
            ushort_t* sAn = smem + ((ch + 1) & 1) * 16384;
            #pragma unroll
            for (int tap = 0; tap < 9; ++tap) {
                const int par = (half + tap) & 1;   // compile-time frag parity

                // counted waits (derived; see header comment)
                if (firstch && tap == 0)     { asm volatile("s_waitcnt vmcnt(0)" ::: "memory"); }
                else if (lastch && tap >= 7) { asm volatile("s_waitcnt vmcnt(0)" ::: "memory"); }
                else if (!lastch && (tap == 6 || tap == 7))
                                             { asm volatile("s_waitcnt vmcnt(6)" ::: "memory"); }
                else                         { asm volatile("s_waitcnt vmcnt(2)" ::: "memory"); }
                asm volatile("s_waitcnt lgkmcnt(0)" ::: "memory");
                __builtin_amdgcn_s_barrier();

                // staging: B(t+3) (3-deep), A' at tap 5
                if (firstch && tap == 0) stage_B(2, ci0, 2);
                if (tap <= 5) {
                    stage_B(tap + 3, ci0, tap % 3);
                    if (tap == 5 && !lastch) stage_A(ci0 + BK, (ch + 1) & 1);
                } else if (!lastch) {
                    stage_B(tap - 6, ci0 + BK, tap % 3);
                }

                // frag prefetch for tap+1 (ping-pong set), then MFMAs for tap t
                if (tap < 8) {
                    const int tp = tap + 1;
                    const int dh2 = tp / 3, dw2 = tp % 3 - 1;
                    ushort_t* sBn = smem + 32768 + (tp % 3) * 8192;
                    if (par == 0) { READ_FRAGS(afB, bfB, dh2, dw2, sBn, sAb) }
                    else          { READ_FRAGS(afA, bfA, dh2, dw2, sBn, sAb) }
                } else if (!lastch) {
                    ushort_t* sBn = smem + 32768;
                    if (par == 0) { READ_FRAGS(afB, bfB, 0, -1, sBn, sAn) }
                    else          { READ_FRAGS(afA, bfA, 0, -1, sBn, sAn) }
                }

                if (par == 0) { MFMA_SET(afA, bfA) }
                else          { MFMA_SET(afB, bfB) }
            }
        }
    }

    // ---- fused epilogue: out = (x-mu)*rstd*(scale+bs+1) + (offset+bo) ----
    int bc_base = b * 256;
    #pragma unroll
    for (int ni = 0; ni < 4; ++ni) {
        int chn = cohalf * 128 + wn * 64 + ni * 16 + (ln & 15);
        float bs = bias_s[chn] + 1.f;
        float bo = bias_o[chn];
        float mu = mean[bc_base + chn];
        float rs = rstd[bc_base + chn];
        #pragma unroll
        for (int mi = 0; mi < 4; ++mi) {
            #pragma unroll
            for (int r = 0; r < 4; ++r) {
                int p = wm * 64 + mi * 16 + ((ln >> 4) << 2) + r;
                int hh = h0 + (p >> 7);
                int ww = p & 127;
                size_t xi = (((size_t)(bc_base + chn)) * H_ + hh) * W_ + ww;
                float xn = (x[xi] - mu) * rs;
                out[xi] = xn * (acc[mi][ni][r] + bs) + (acc[mi][ni + 4][r] + bo);
            }
        }
    }
}

// ---------------- launcher ----------------
extern "C" void kernel_launch(void* const* d_in, const int* in_sizes, int n_in,
                              void* d_out, int out_size, void* d_ws, size_t ws_size,
                              hipStream_t stream)
{
    const float* x        = (const float*)d_in[0];
    const float* segmap   = (const float*)d_in[1];
    const float* style    = (const float*)d_in[2];
    const float* w_shared = (const float*)d_in[3];
    const float* b_shared = (const float*)d_in[4];
    const float* w_gamma  = (const float*)d_in[5];
    const float* b_gamma  = (const float*)d_in[6];
    const float* w_beta   = (const float*)d_in[7];
    const float* b_beta   = (const float*)d_in[8];
    const float* w_sgamma = (const float*)d_in[9];
    const float* b_sgamma = (const float*)d_in[10];
    const float* w_sbeta  = (const float*)d_in[11];
    const float* b_sbeta  = (const float*)d_in[12];
    const float* alpha_beta  = (const float*)d_in[13];
    const float* alpha_gamma = (const float*)d_in[14];
    float* out = (float*)d_out;

    char* ws = (char*)d_ws;
    float*    ws_mean  = (float*)(ws + 0);            // 2048 f32
    float*    ws_rstd  = (float*)(ws + 8192);         // 2048 f32
    float*    ws_bs    = (float*)(ws + 16384);        // 256 f32
    float*    ws_bo    = (float*)(ws + 18432);        // 256 f32
    ushort_t* ws_Wt    = (ushort_t*)(ws + 20480);     // 9*512*640 bf16 = 5.9 MB
    ushort_t* ws_zp    = (ushort_t*)(ws + 6 * 1024 * 1024 - 65536);  // 32KB zero page
    ushort_t* ws_U     = (ushort_t*)(ws + 6 * 1024 * 1024);  // 8*128*128*640 bf16 = 167.8 MB

    (void)hipFuncSetAttribute((const void*)k_conv,
                              hipFuncAttributeMaxDynamicSharedMemorySize, 114688);

    k_prep<<<dim3(2048), dim3(256), 0, stream>>>(w_gamma, w_beta, w_sgamma, w_sbeta,
                                                 b_gamma, b_beta, b_sgamma, b_sbeta,
                                                 alpha_beta, alpha_gamma, ws_Wt, ws_bs, ws_bo,
                                                 (float*)ws_zp);
    k_stats<<<dim3(2048), dim3(256), 0, stream>>>(x, ws_mean, ws_rstd);
    k_buildU<<<dim3(1024), dim3(256), 0, stream>>>(segmap, style, w_shared, b_shared, ws_U);
    k_conv<<<dim3(1024), dim3(512), 114688, stream>>>(ws_U, ws_Wt, ws_zp, x, ws_mean, ws_rstd,
                                                      ws_bs, ws_bo, out);
}

// Round 10
// 1975.731 us; speedup vs baseline: 1.2806x; 1.2806x over previous
//
#include <hip/hip_runtime.h>
#include <hip/hip_bf16.h>
#include <cstdint>

#define B_ 8
#define LABEL_NC 19
#define H_ 128
#define W_ 128
#define UC 640
#define EPS_ 1e-5f

typedef __attribute__((ext_vector_type(8))) short s8v;    // 8 bf16 (4 VGPR) MFMA frag
typedef __attribute__((ext_vector_type(4))) float f4v;    // MFMA acc
typedef unsigned short ushort_t;

__device__ __forceinline__ ushort_t f2b(float f) {
    union { float f; uint32_t u; } a; a.f = f;
    uint32_t u = a.u;
    return (ushort_t)((u + 0x7FFFu + ((u >> 16) & 1u)) >> 16);  // RNE
}

__device__ __forceinline__ void gl2lds16(const ushort_t* g, ushort_t* l) {
    __builtin_amdgcn_global_load_lds(
        (const __attribute__((address_space(1))) unsigned int*)g,
        (__attribute__((address_space(3))) unsigned int*)l, 16, 0, 0);
}

// ---------------- kernel 0: fold blend weights into combined conv weights ----------------
// Wt layout: [tap(9)][co(512)][ci(640)] bf16.  co<256 = scale (gamma), co>=256 = offset (beta).
__global__ void __launch_bounds__(256) k_prep(
    const float* __restrict__ w_gamma, const float* __restrict__ w_beta,
    const float* __restrict__ w_sgamma, const float* __restrict__ w_sbeta,
    const float* __restrict__ b_gamma, const float* __restrict__ b_beta,
    const float* __restrict__ b_sgamma, const float* __restrict__ b_sbeta,
    const float* __restrict__ alpha_beta, const float* __restrict__ alpha_gamma,
    ushort_t* __restrict__ Wt, float* __restrict__ bias_s, float* __restrict__ bias_o)
{
    float wb = 1.f / (1.f + __expf(-alpha_beta[0]));
    float wg = 1.f / (1.f + __expf(-alpha_gamma[0]));
    int gid = blockIdx.x * 256 + threadIdx.x;
    if (gid < 256) bias_s[gid] = wg * b_sgamma[gid] + (1.f - wg) * b_gamma[gid];
    else if (gid < 512) bias_o[gid - 256] = wb * b_sbeta[gid - 256] + (1.f - wb) * b_beta[gid - 256];

    const int total = 9 * 512 * 640;
    for (int idx = gid; idx < total; idx += gridDim.x * 256) {
        int tap = idx / (512 * 640);
        int r = idx - tap * (512 * 640);
        int co = r / 640, ci = r - co * 640;
        int kh = tap / 3, kw = tap - kh * 3;
        float v;
        if (co < 256) {
            if (ci < 128) v = (1.f - wg) * w_gamma[((co * 128 + ci) * 3 + kh) * 3 + kw];
            else          v = wg * w_sgamma[((co * 512 + (ci - 128)) * 3 + kh) * 3 + kw];
        } else {
            int c2 = co - 256;
            if (ci < 128) v = (1.f - wb) * w_beta[((c2 * 128 + ci) * 3 + kh) * 3 + kw];
            else          v = wb * w_sbeta[((c2 * 512 + (ci - 128)) * 3 + kh) * 3 + kw];
        }
        Wt[idx] = f2b(v);
    }
}

// ---------------- kernel 1: per-(b,c) instance-norm stats ----------------
__global__ void __launch_bounds__(256) k_stats(const float* __restrict__ x,
                                               float* __restrict__ mean, float* __restrict__ rstd)
{
    int bc = blockIdx.x;  // b*256+c
    const float4* p = (const float4*)(x + (size_t)bc * (H_ * W_));
    float s = 0.f, s2 = 0.f;
    for (int i = threadIdx.x; i < H_ * W_ / 4; i += 256) {
        float4 v = p[i];
        s += v.x + v.y + v.z + v.w;
        s2 += v.x * v.x + v.y * v.y + v.z * v.z + v.w * v.w;
    }
    #pragma unroll
    for (int o = 32; o > 0; o >>= 1) { s += __shfl_xor(s, o); s2 += __shfl_xor(s2, o); }
    __shared__ float red[8];
    int wave = threadIdx.x >> 6, lane = threadIdx.x & 63;
    if (lane == 0) { red[wave] = s; red[wave + 4] = s2; }
    __syncthreads();
    if (threadIdx.x == 0) {
        float ts = red[0] + red[1] + red[2] + red[3];
        float t2 = red[4] + red[5] + red[6] + red[7];
        float m = ts * (1.f / 16384.f);
        float v = t2 * (1.f / 16384.f) - m * m;
        mean[bc] = m;
        rstd[bc] = rsqrtf(v + EPS_);
    }
}

// ---------------- kernel 2: build U[b][h][w][640] bf16 (NHWC) ----------------
__global__ void __launch_bounds__(256) k_buildU(
    const float* __restrict__ segmap, const float* __restrict__ style,
    const float* __restrict__ w_shared, const float* __restrict__ b_shared,
    ushort_t* __restrict__ U)
{
    int bh = blockIdx.x;
    int b = bh >> 7, h = bh & 127;
    __shared__ float seg[3][LABEL_NC][W_];   // rows h-1,h,h+1
    const float* segb = segmap + (size_t)b * (LABEL_NC * H_ * W_);
    for (int idx = threadIdx.x; idx < 3 * LABEL_NC * W_; idx += 256) {
        int w = idx & 127;
        int l = (idx >> 7) % LABEL_NC;
        int rr = idx / (LABEL_NC * W_);
        int hh = h + rr - 1;
        seg[rr][l][w] = (hh >= 0 && hh < H_) ? segb[((size_t)l * H_ + hh) * W_ + w] : 0.f;
    }
    __syncthreads();

    int t = threadIdx.x;
    int w = t & 127;
    int grp = __builtin_amdgcn_readfirstlane(t >> 7);   // 0 or 1, wave-uniform
    ushort_t* Urow = U + (((size_t)(b * H_ + h)) * W_ + w) * UC;

    for (int cb = 0; cb < 4; ++cb) {
        int co0 = grp * 64 + cb * 16;
        float acc[16];
        #pragma unroll
        for (int i = 0; i < 16; ++i) acc[i] = b_shared[co0 + i];
        for (int l = 0; l < LABEL_NC; ++l) {
            #pragma unroll
            for (int kh = 0; kh < 3; ++kh) {
                float sm = (w > 0)   ? seg[kh][l][w - 1] : 0.f;
                float s0 = seg[kh][l][w];
                float sp = (w < 127) ? seg[kh][l][w + 1] : 0.f;
                const float* wp = w_shared + ((size_t)co0 * LABEL_NC + l) * 9 + kh * 3;
                #pragma unroll
                for (int i = 0; i < 16; ++i) {
                    const float* wpi = wp + i * (LABEL_NC * 9);
                    acc[i] += sm * wpi[0] + s0 * wpi[1] + sp * wpi[2];
                }
            }
        }
        #pragma unroll
        for (int i = 0; i < 16; ++i)
            Urow[co0 + i] = f2b(acc[i] > 0.f ? acc[i] : 0.f);
    }

    float segr[LABEL_NC];
    #pragma unroll
    for (int l = 0; l < LABEL_NC; ++l) segr[l] = seg[1][l][w];
    const float* styb = style + (size_t)b * (LABEL_NC * 512);
    for (int sb = 0; sb < 16; ++sb) {
        int s0 = grp * 256 + sb * 16;
        float acc[16];
        #pragma unroll
        for (int i = 0; i < 16; ++i) acc[i] = 0.f;
        for (int l = 0; l < LABEL_NC; ++l) {
            const float* sp = styb + l * 512 + s0;
            float sl = segr[l];
            #pragma unroll
            for (int i = 0; i < 16; ++i) acc[i] += sl * sp[i];
        }
        #pragma unroll
        for (int i = 0; i < 16; ++i) Urow[128 + s0 + i] = f2b(acc[i]);
    }
}

// ---------------- kernel 3: main implicit-GEMM conv + fused epilogue ----------------
// 512 threads (8 waves, 4wm x 2wn). M = 256 px (2 rows), N = 256 (128 scale + 128 offset).
// A-operand read DIRECTLY global->VGPR (4 dwordx4/wave/tap from U, L2-resident; halo by
// clamped address + per-fragment zero guard). LDS holds ONLY B: 3 slots x 16KB = 48KB
// static -> 3 blocks/CU; blocks drift in phase and fill each other's pipe gaps.
// B staged 2-ahead into slot (g+2)%3 (= (g-1)%3, whose reads finished last body).
// Steady vmcnt(2); drain only at the final body.
// Halo guards (R9 bug fix): q<0 only at global pixel 0 -> (wm&1)==0 & mi==0 & lane0;
// q>127 only at pixel 127 -> (wm&1)==1 & mi==3 & lane15. Guards must include (wm&1).
// B LDS slot swizzle: phys_slot = data_slot ^ ((row>>1)&3) (conflict-free, R6-verified).
#define BK 32

__global__ void __launch_bounds__(512, 1) k_conv(
    const ushort_t* __restrict__ U, const ushort_t* __restrict__ Wt,
    const float* __restrict__ x, const float* __restrict__ mean, const float* __restrict__ rstd,
    const float* __restrict__ bias_s, const float* __restrict__ bias_o,
    float* __restrict__ out)
{
    // bijective XCD-chunk swizzle (nwg=1024, 128 per XCD); cohalf pairs share an XCD (L2 reuse)
    int orig = blockIdx.x;
    int wg = (orig & 7) * 128 + (orig >> 3);
    int mtile = wg >> 1;
    int cohalf = wg & 1;
    int b = mtile >> 6;
    int h0 = (mtile & 63) << 1;

    __shared__ ushort_t sB[3 * 8192];   // 48KB static

    int t = threadIdx.x;
    int wv = t >> 6, ln = t & 63;
    int wm = wv >> 1, wn = wv & 1;
    int sd = ln >> 4;                 // 16B k-slot

    const ushort_t* Ub = U + (size_t)b * (H_ * W_ * UC);

    // ---- A global addressing precompute ----
    int pxb = (wm & 1) * 64 + (ln & 15);
    size_t rowoff[3];
    #pragma unroll
    for (int dh = 0; dh < 3; ++dh) {
        int hh = h0 + (wm >> 1) + dh - 1;
        int hc = hh < 0 ? 0 : (hh > 127 ? 127 : hh);
        rowoff[dh] = (size_t)hc * (W_ * UC);
    }
    bool zr0 = (h0 + (wm >> 1) - 1) < 0;      // only dhp1==0 can be OOB low
    bool zr2 = (h0 + (wm >> 1) + 1) > 127;    // only dhp1==2 can be OOB high
    int qoff[3][4];
    #pragma unroll
    for (int dwi = 0; dwi < 3; ++dwi)
        #pragma unroll
        for (int mi = 0; mi < 4; ++mi) {
            int q = pxb + mi * 16 + dwi - 1;
            int qc = q < 0 ? 0 : (q > 127 ? 127 : q);
            qoff[dwi][mi] = qc * UC + sd * 8;
        }
    // per-fragment halo guards (include wm&1 -- the R9 bug)
    bool zlo = ((wm & 1) == 0) && ((ln & 15) == 0);    // pixel 0, dw=-1, mi=0
    bool zhi = ((wm & 1) == 1) && ((ln & 15) == 15);   // pixel 127, dw=+1, mi=3

    f4v acc[4][8] = {};   // [mi][ni]; ni<4 scale, ni>=4 offset (same channels)

    auto stage_B = [&](int tapX, int ci0X, int bi) {   // 2 loads/thread -> 16KB
        ushort_t* base = sB + bi * 8192;
        #pragma unroll
        for (int j = 0; j < 2; ++j) {
            int issue = wv * 2 + j;            // 16 issues of 1KB
            int c = issue * 16 + (ln >> 2);    // LDS row (0..255)
            int sl = (ln & 3) ^ ((c >> 1) & 3);
            int gq = (c >> 6) & 1;
            int cbase = ((c >> 7) << 6) + (c & 63);
            int co = gq * 256 + cohalf * 128 + cbase;
            const ushort_t* src = Wt + ((size_t)tapX * 512 + co) * UC + ci0X + (sl << 3);
            gl2lds16(src, base + (size_t)issue * 512);
        }
    };

    // ---- prologue: B(0), B(1) in flight ----
    stage_B(0, 0, 0);
    stage_B(1, 0, 1);

    for (int ch = 0; ch < 20; ++ch) {
        int ci0 = ch * BK;
        #pragma unroll
        for (int tap = 0; tap < 9; ++tap) {
            const int dhp1 = tap / 3;          // compile-time
            const int dwi = tap % 3;           // dw = dwi-1
            const int bi = tap % 3;            // g = 9ch+tap ≡ tap (mod 3)

            if (tap == 8 && ch == 19) { asm volatile("s_waitcnt vmcnt(0)" ::: "memory"); }
            else                      { asm volatile("s_waitcnt vmcnt(2)" ::: "memory"); }
            __builtin_amdgcn_s_barrier();

            // ---- A-frags: global -> VGPR (issued early for latency cover) ----
            const ushort_t* arow = Ub + rowoff[dhp1] + ci0;
            s8v av[4];
            #pragma unroll
            for (int mi = 0; mi < 4; ++mi)
                av[mi] = *(const s8v*)(arow + qoff[dwi][mi]);

            // ---- stage B(g+2) into slot (tap+2)%3 ----
            {
                const int tap2 = (tap + 2) % 9;
                int ch2 = ch + (tap + 2) / 9;
                if (ch2 < 20) stage_B(tap2, ch2 * BK, (tap + 2) % 3);
            }

            // ---- halo zero fixes ----
            s8v z = {};
            if (dhp1 == 0) { if (zr0) { av[0] = z; av[1] = z; av[2] = z; av[3] = z; } }
            if (dhp1 == 2) { if (zr2) { av[0] = z; av[1] = z; av[2] = z; av[3] = z; } }
            if (dwi == 0) { if (zlo) av[0] = z; }
            if (dwi == 2) { if (zhi) av[3] = z; }

            // ---- B-frags from LDS ----
            ushort_t* sBb = sB + bi * 8192;
            s8v bf[8];
            #pragma unroll
            for (int ni = 0; ni < 8; ++ni) {
                int c = wn * 128 + (ni >> 2) * 64 + (ni & 3) * 16 + (ln & 15);
                bf[ni] = *(const s8v*)&sBb[(size_t)((c << 2) + (sd ^ ((c >> 1) & 3))) * 8];
            }

            __builtin_amdgcn_s_setprio(1);
            #pragma unroll
            for (int mi = 0; mi < 4; ++mi)
                #pragma unroll
                for (int ni = 0; ni < 8; ++ni)
                    acc[mi][ni] = __builtin_amdgcn_mfma_f32_16x16x32_bf16(
                        av[mi], bf[ni], acc[mi][ni], 0, 0, 0);
            __builtin_amdgcn_s_setprio(0);
        }
    }

    // ---- fused epilogue (float4): out = (x-mu)*rstd*(scale+bs+1) + (offset+bo) ----
    int bc_base = b * 256;
    int hh = h0 + (wm >> 1);
    #pragma unroll
    for (int ni = 0; ni < 4; ++ni) {
        int chn = cohalf * 128 + wn * 64 + ni * 16 + (ln & 15);
        float bs = bias_s[chn] + 1.f;
        float bo = bias_o[chn];
        float mu = mean[bc_base + chn];
        float rs = rstd[bc_base + chn];
        #pragma unroll
        for (int mi = 0; mi < 4; ++mi) {
            int p = (wm & 1) * 64 + mi * 16 + ((ln >> 4) << 2);
            size_t xi = (((size_t)(bc_base + chn)) * H_ + hh) * W_ + p;
            float4 xv = *(const float4*)&x[xi];
            float4 ov;
            ov.x = (xv.x - mu) * rs * (acc[mi][ni][0] + bs) + (acc[mi][ni + 4][0] + bo);
            ov.y = (xv.y - mu) * rs * (acc[mi][ni][1] + bs) + (acc[mi][ni + 4][1] + bo);
            ov.z = (xv.z - mu) * rs * (acc[mi][ni][2] + bs) + (acc[mi][ni + 4][2] + bo);
            ov.w = (xv.w - mu) * rs * (acc[mi][ni][3] + bs) + (acc[mi][ni + 4][3] + bo);
            *(float4*)&out[xi] = ov;
        }
    }
}

// ---------------- launcher ----------------
extern "C" void kernel_launch(void* const* d_in, const int* in_sizes, int n_in,
                              void* d_out, int out_size, void* d_ws, size_t ws_size,
                              hipStream_t stream)
{
    const float* x        = (const float*)d_in[0];
    const float* segmap   = (const float*)d_in[1];
    const float* style    = (const float*)d_in[2];
    const float* w_shared = (const float*)d_in[3];
    const float* b_shared = (const float*)d_in[4];
    const float* w_gamma  = (const float*)d_in[5];
    const float* b_gamma  = (const float*)d_in[6];
    const float* w_beta   = (const float*)d_in[7];
    const float* b_beta   = (const float*)d_in[8];
    const float* w_sgamma = (const float*)d_in[9];
    const float* b_sgamma = (const float*)d_in[10];
    const float* w_sbeta  = (const float*)d_in[11];
    const float* b_sbeta  = (const float*)d_in[12];
    const float* alpha_beta  = (const float*)d_in[13];
    const float* alpha_gamma = (const float*)d_in[14];
    float* out = (float*)d_out;

    char* ws = (char*)d_ws;
    float*    ws_mean  = (float*)(ws + 0);            // 2048 f32
    float*    ws_rstd  = (float*)(ws + 8192);         // 2048 f32
    float*    ws_bs    = (float*)(ws + 16384);        // 256 f32
    float*    ws_bo    = (float*)(ws + 18432);        // 256 f32
    ushort_t* ws_Wt    = (ushort_t*)(ws + 20480);     // 9*512*640 bf16 = 5.9 MB
    ushort_t* ws_U     = (ushort_t*)(ws + 6 * 1024 * 1024);  // 8*128*128*640 bf16 = 167.8 MB

    k_prep<<<dim3(2048), dim3(256), 0, stream>>>(w_gamma, w_beta, w_sgamma, w_sbeta,
                                                 b_gamma, b_beta, b_sgamma, b_sbeta,
                                                 alpha_beta, alpha_gamma, ws_Wt, ws_bs, ws_bo);
    k_stats<<<dim3(2048), dim3(256), 0, stream>>>(x, ws_mean, ws_rstd);
    k_buildU<<<dim3(1024), dim3(256), 0, stream>>>(segmap, style, w_shared, b_shared, ws_U);
    k_conv<<<dim3(1024), dim3(512), 0, stream>>>(ws_U, ws_Wt, x, ws_mean, ws_rstd,
                                                 ws_bs, ws_bo, out);
}

// Round 11
// 958.074 us; speedup vs baseline: 2.6408x; 2.0622x over previous
//
#include <hip/hip_runtime.h>
#include <hip/hip_bf16.h>
#include <cstdint>

#define B_ 8
#define LABEL_NC 19
#define H_ 128
#define W_ 128
#define UC 640
#define EPS_ 1e-5f

typedef __attribute__((ext_vector_type(8))) short s8v;    // 8 bf16 (4 VGPR) MFMA frag
typedef __attribute__((ext_vector_type(4))) float f4v;    // MFMA acc
typedef __attribute__((ext_vector_type(4))) int i4v;      // 16B ld/st
typedef unsigned short ushort_t;

__device__ __forceinline__ ushort_t f2b(float f) {
    union { float f; uint32_t u; } a; a.f = f;
    uint32_t u = a.u;
    return (ushort_t)((u + 0x7FFFu + ((u >> 16) & 1u)) >> 16);  // RNE
}

__device__ __forceinline__ void gl2lds16(const ushort_t* g, ushort_t* l) {
    __builtin_amdgcn_global_load_lds(
        (const __attribute__((address_space(1))) unsigned int*)g,
        (__attribute__((address_space(3))) unsigned int*)l, 16, 0, 0);
}

// ---------------- kernel 0: fold blend weights into combined conv weights ----------------
// Wt layout: [tap(9)][co(512)][ci(640)] bf16.  co<256 = scale (gamma), co>=256 = offset (beta).
// Also zeroes a 32KB zero-page used by k_conv's halo staging.
__global__ void __launch_bounds__(256) k_prep(
    const float* __restrict__ w_gamma, const float* __restrict__ w_beta,
    const float* __restrict__ w_sgamma, const float* __restrict__ w_sbeta,
    const float* __restrict__ b_gamma, const float* __restrict__ b_beta,
    const float* __restrict__ b_sgamma, const float* __restrict__ b_sbeta,
    const float* __restrict__ alpha_beta, const float* __restrict__ alpha_gamma,
    ushort_t* __restrict__ Wt, float* __restrict__ bias_s, float* __restrict__ bias_o,
    float* __restrict__ zpage)
{
    float wb = 1.f / (1.f + __expf(-alpha_beta[0]));
    float wg = 1.f / (1.f + __expf(-alpha_gamma[0]));
    int gid = blockIdx.x * 256 + threadIdx.x;
    if (gid < 256) bias_s[gid] = wg * b_sgamma[gid] + (1.f - wg) * b_gamma[gid];
    else if (gid < 512) bias_o[gid - 256] = wb * b_sbeta[gid - 256] + (1.f - wb) * b_beta[gid - 256];
    if (gid < 8192) zpage[gid] = 0.f;   // 32KB zero page

    const int total = 9 * 512 * 640;
    for (int idx = gid; idx < total; idx += gridDim.x * 256) {
        int tap = idx / (512 * 640);
        int r = idx - tap * (512 * 640);
        int co = r / 640, ci = r - co * 640;
        int kh = tap / 3, kw = tap - kh * 3;
        float v;
        if (co < 256) {
            if (ci < 128) v = (1.f - wg) * w_gamma[((co * 128 + ci) * 3 + kh) * 3 + kw];
            else          v = wg * w_sgamma[((co * 512 + (ci - 128)) * 3 + kh) * 3 + kw];
        } else {
            int c2 = co - 256;
            if (ci < 128) v = (1.f - wb) * w_beta[((c2 * 128 + ci) * 3 + kh) * 3 + kw];
            else          v = wb * w_sbeta[((c2 * 512 + (ci - 128)) * 3 + kh) * 3 + kw];
        }
        Wt[idx] = f2b(v);
    }
}

// ---------------- kernel 1: per-(b,c) instance-norm stats ----------------
__global__ void __launch_bounds__(256) k_stats(const float* __restrict__ x,
                                               float* __restrict__ mean, float* __restrict__ rstd)
{
    int bc = blockIdx.x;  // b*256+c
    const float4* p = (const float4*)(x + (size_t)bc * (H_ * W_));
    float s = 0.f, s2 = 0.f;
    for (int i = threadIdx.x; i < H_ * W_ / 4; i += 256) {
        float4 v = p[i];
        s += v.x + v.y + v.z + v.w;
        s2 += v.x * v.x + v.y * v.y + v.z * v.z + v.w * v.w;
    }
    #pragma unroll
    for (int o = 32; o > 0; o >>= 1) { s += __shfl_xor(s, o); s2 += __shfl_xor(s2, o); }
    __shared__ float red[8];
    int wave = threadIdx.x >> 6, lane = threadIdx.x & 63;
    if (lane == 0) { red[wave] = s; red[wave + 4] = s2; }
    __syncthreads();
    if (threadIdx.x == 0) {
        float ts = red[0] + red[1] + red[2] + red[3];
        float t2 = red[4] + red[5] + red[6] + red[7];
        float m = ts * (1.f / 16384.f);
        float v = t2 * (1.f / 16384.f) - m * m;
        mean[bc] = m;
        rstd[bc] = rsqrtf(v + EPS_);
    }
}

// ---------------- kernel 2: build U[b][h][w][640] bf16 (NHWC) ----------------
// R11: vectorized output -- each 16-channel batch packed in registers and stored as
// 2x int4 (32B contiguous/lane) instead of 16 scalar 2B stores (64x fewer L2 sectors).
__global__ void __launch_bounds__(256) k_buildU(
    const float* __restrict__ segmap, const float* __restrict__ style,
    const float* __restrict__ w_shared, const float* __restrict__ b_shared,
    ushort_t* __restrict__ U)
{
    int bh = blockIdx.x;
    int b = bh >> 7, h = bh & 127;
    __shared__ float seg[3][LABEL_NC][W_];   // rows h-1,h,h+1
    const float* segb = segmap + (size_t)b * (LABEL_NC * H_ * W_);
    for (int idx = threadIdx.x; idx < 3 * LABEL_NC * W_; idx += 256) {
        int w = idx & 127;
        int l = (idx >> 7) % LABEL_NC;
        int rr = idx / (LABEL_NC * W_);
        int hh = h + rr - 1;
        seg[rr][l][w] = (hh >= 0 && hh < H_) ? segb[((size_t)l * H_ + hh) * W_ + w] : 0.f;
    }
    __syncthreads();

    int t = threadIdx.x;
    int w = t & 127;
    int grp = __builtin_amdgcn_readfirstlane(t >> 7);   // 0 or 1, wave-uniform
    ushort_t* Urow = U + (((size_t)(b * H_ + h)) * W_ + w) * UC;

    union pack16 { ushort_t u[16]; i4v v[2]; };

    // part A: actv channels grp*64 .. +64, batches of 16
    for (int cb = 0; cb < 4; ++cb) {
        int co0 = grp * 64 + cb * 16;
        float acc[16];
        #pragma unroll
        for (int i = 0; i < 16; ++i) acc[i] = b_shared[co0 + i];
        for (int l = 0; l < LABEL_NC; ++l) {
            #pragma unroll
            for (int kh = 0; kh < 3; ++kh) {
                float sm = (w > 0)   ? seg[kh][l][w - 1] : 0.f;
                float s0 = seg[kh][l][w];
                float sp = (w < 127) ? seg[kh][l][w + 1] : 0.f;
                const float* wp = w_shared + ((size_t)co0 * LABEL_NC + l) * 9 + kh * 3;
                #pragma unroll
                for (int i = 0; i < 16; ++i) {
                    const float* wpi = wp + i * (LABEL_NC * 9);
                    acc[i] += sm * wpi[0] + s0 * wpi[1] + sp * wpi[2];
                }
            }
        }
        pack16 pk;
        #pragma unroll
        for (int i = 0; i < 16; ++i) pk.u[i] = f2b(acc[i] > 0.f ? acc[i] : 0.f);
        *(i4v*)(Urow + co0) = pk.v[0];
        *(i4v*)(Urow + co0 + 8) = pk.v[1];
    }

    // part B: style_map channels grp*256 .. +256, batches of 16
    float segr[LABEL_NC];
    #pragma unroll
    for (int l = 0; l < LABEL_NC; ++l) segr[l] = seg[1][l][w];
    const float* styb = style + (size_t)b * (LABEL_NC * 512);
    for (int sb = 0; sb < 16; ++sb) {
        int s0 = grp * 256 + sb * 16;
        float acc[16];
        #pragma unroll
        for (int i = 0; i < 16; ++i) acc[i] = 0.f;
        for (int l = 0; l < LABEL_NC; ++l) {
            const float* sp = styb + l * 512 + s0;
            float sl = segr[l];
            #pragma unroll
            for (int i = 0; i < 16; ++i) acc[i] += sl * sp[i];
        }
        pack16 pk;
        #pragma unroll
        for (int i = 0; i < 16; ++i) pk.u[i] = f2b(acc[i]);
        *(i4v*)(Urow + 128 + s0) = pk.v[0];
        *(i4v*)(Urow + 128 + s0 + 8) = pk.v[1];
    }
}

// ---------------- kernel 3: main implicit-GEMM conv + fused epilogue (R6, 633us) ----------
// 512 threads (8 waves, 4wm x 2wn). M = 256 px (2 rows), N = 256 (128 scale + 128 offset).
// BK=32. LDS: A dbuf 2x32KB + B triple-buf 3x16KB = 112KB, 1 block/CU (reg-capped anyway:
// 128 arch + 128 acc = 256/wave -> 2 waves/SIMD).
// Deep pipeline: B(g) staged at g-2; raw s_barrier + counted vmcnt; A' staged at tap 7.
// LDS slot swizzle: phys_slot = data_slot ^ ((row>>1)&3) -> conflict-free (R6-verified).
#define BK 32

__global__ void __launch_bounds__(512, 1) k_conv(
    const ushort_t* __restrict__ U, const ushort_t* __restrict__ Wt,
    const ushort_t* __restrict__ zp,
    const float* __restrict__ x, const float* __restrict__ mean, const float* __restrict__ rstd,
    const float* __restrict__ bias_s, const float* __restrict__ bias_o,
    float* __restrict__ out)
{
    // bijective XCD-chunk swizzle (nwg=1024, 128 per XCD)
    int orig = blockIdx.x;
    int wg = (orig & 7) * 128 + (orig >> 3);
    int mtile = wg >> 1;
    int cohalf = wg & 1;
    int b = mtile >> 6;
    int h0 = (mtile & 63) << 1;

    extern __shared__ ushort_t smem[];
    // smem + ab*16384        : sA[2]  (each 4 rows x 128 px x 32 ci = 32KB)
    // smem + 32768 + bi*8192 : sB[3]  (each 256 ch x 32 ci = 16KB)

    int t = threadIdx.x;
    int wv = t >> 6, ln = t & 63;
    int wm = wv >> 1, wn = wv & 1;

    const ushort_t* Ub = U + (size_t)b * (H_ * W_ * UC);

    f4v acc[4][8] = {};   // [mi][ni]; ni<4 scale, ni>=4 offset (same channels)

    auto stage_A = [&](int ci0, int ab) {      // 4 loads/thread -> 32KB
        ushort_t* sAb = smem + ab * 16384;
        #pragma unroll
        for (int i = 0; i < 4; ++i) {
            int issue = wv * 4 + i;            // 32 issues of 1KB
            int hh = h0 - 1 + (issue >> 3);    // wave-uniform row
            int w = issue * 16 + (ln >> 2);
            int sl = (ln & 3) ^ ((w >> 1) & 3);    // inverse-swizzled source slot
            const ushort_t* src = (hh >= 0 && hh < H_)
                ? Ub + ((size_t)hh * W_ + (w & 127)) * UC + ci0 + (sl << 3)
                : zp + (size_t)ln * 8;
            gl2lds16(src, sAb + (size_t)issue * 512);
        }
    };
    auto stage_B = [&](int tapX, int ci0X, int bi) {   // 2 loads/thread -> 16KB
        ushort_t* base = smem + 32768 + bi * 8192;
        #pragma unroll
        for (int j = 0; j < 2; ++j) {
            int issue = wv * 2 + j;            // 16 issues of 1KB
            int c = issue * 16 + (ln >> 2);    // LDS row (0..255)
            int sl = (ln & 3) ^ ((c >> 1) & 3);
            int gq = (c >> 6) & 1;
            int cbase = ((c >> 7) << 6) + (c & 63);
            int co = gq * 256 + cohalf * 128 + cbase;
            const ushort_t* src = Wt + ((size_t)tapX * 512 + co) * UC + ci0X + (sl << 3);
            gl2lds16(src, base + (size_t)issue * 512);
        }
    };

    // ---- prologue: A(ch0), B(g=0), B(g=1) ----
    stage_A(0, 0);
    stage_B(0, 0, 0);
    stage_B(1, 0, 1);

    for (int ch = 0; ch < 20; ++ch) {
        int ci0 = ch * BK;
        ushort_t* sAb = smem + (ch & 1) * 16384;
        bool lastch = (ch == 19);
        #pragma unroll
        for (int tap = 0; tap < 9; ++tap) {
            const int dhp1 = tap / 3;            // compile-time after unroll
            const int dw = tap - dhp1 * 3 - 1;
            const int bi = tap % 3;              // 9 % 3 == 0 -> per-tap constant
            const int bi2 = (tap + 2) % 3;

            // counted waits: own B (and A at chunk entry) landed; newer loads in flight
            if (tap == 8) {
                if (lastch) { asm volatile("s_waitcnt vmcnt(0)" ::: "memory"); }
                else        { asm volatile("s_waitcnt vmcnt(6)" ::: "memory"); }
            } else          { asm volatile("s_waitcnt vmcnt(2)" ::: "memory"); }
            __builtin_amdgcn_s_barrier();

            // prefetch body g+2 (B), and next chunk's A at tap 7 (after B, order matters)
            if (tap < 7)        stage_B(tap + 2, ci0, bi2);
            else if (!lastch) {
                if (tap == 7) { stage_B(0, ci0 + BK, bi2); stage_A(ci0 + BK, (ch + 1) & 1); }
                else          stage_B(1, ci0 + BK, bi2);
            }

            // ---- compute: sA rows dhp1..dhp1+1 (dw shift), sB[bi] ----
            ushort_t* sBb = smem + 32768 + bi * 8192;
            int sd = ln >> 4;                 // 16B k-slot
            s8v af[4];
            #pragma unroll
            for (int mi = 0; mi < 4; ++mi) {
                int p = wm * 64 + mi * 16 + (ln & 15);
                int q = (p & 127) + dw;
                int qc = q < 0 ? 0 : (q > 127 ? 127 : q);
                int r = (p >> 7) + dhp1;
                s8v v = *(const s8v*)&sAb[(size_t)(((r * 128 + qc) << 2) + (sd ^ ((qc >> 1) & 3))) * 8];
                if (dw != 0 && (q < 0 || q > 127)) { s8v z = {}; v = z; }
                af[mi] = v;
            }
            s8v bf[8];
            #pragma unroll
            for (int ni = 0; ni < 8; ++ni) {
                int c = wn * 128 + (ni >> 2) * 64 + (ni & 3) * 16 + (ln & 15);
                bf[ni] = *(const s8v*)&sBb[(size_t)((c << 2) + (sd ^ ((c >> 1) & 3))) * 8];
            }
            __builtin_amdgcn_s_setprio(1);
            #pragma unroll
            for (int mi = 0; mi < 4; ++mi)
                #pragma unroll
                for (int ni = 0; ni < 8; ++ni)
                    acc[mi][ni] = __builtin_amdgcn_mfma_f32_16x16x32_bf16(
                        af[mi], bf[ni], acc[mi][ni], 0, 0, 0);
            __builtin_amdgcn_s_setprio(0);
        }
    }

    // ---- fused epilogue: out = (x-mu)*rstd*(scale+bs+1) + (offset+bo) ----
    int bc_base = b * 256;
    #pragma unroll
    for (int ni = 0; ni < 4; ++ni) {
        int chn = cohalf * 128 + wn * 64 + ni * 16 + (ln & 15);
        float bs = bias_s[chn] + 1.f;
        float bo = bias_o[chn];
        float mu = mean[bc_base + chn];
        float rs = rstd[bc_base + chn];
        #pragma unroll
        for (int mi = 0; mi < 4; ++mi) {
            #pragma unroll
            for (int r = 0; r < 4; ++r) {
                int p = wm * 64 + mi * 16 + ((ln >> 4) << 2) + r;
                int hh = h0 + (p >> 7);
                int ww = p & 127;
                size_t xi = (((size_t)(bc_base + chn)) * H_ + hh) * W_ + ww;
                float xn = (x[xi] - mu) * rs;
                out[xi] = xn * (acc[mi][ni][r] + bs) + (acc[mi][ni + 4][r] + bo);
            }
        }
    }
}

// ---------------- launcher ----------------
extern "C" void kernel_launch(void* const* d_in, const int* in_sizes, int n_in,
                              void* d_out, int out_size, void* d_ws, size_t ws_size,
                              hipStream_t stream)
{
    const float* x        = (const float*)d_in[0];
    const float* segmap   = (const float*)d_in[1];
    const float* style    = (const float*)d_in[2];
    const float* w_shared = (const float*)d_in[3];
    const float* b_shared = (const float*)d_in[4];
    const float* w_gamma  = (const float*)d_in[5];
    const float* b_gamma  = (const float*)d_in[6];
    const float* w_beta   = (const float*)d_in[7];
    const float* b_beta   = (const float*)d_in[8];
    const float* w_sgamma = (const float*)d_in[9];
    const float* b_sgamma = (const float*)d_in[10];
    const float* w_sbeta  = (const float*)d_in[11];
    const float* b_sbeta  = (const float*)d_in[12];
    const float* alpha_beta  = (const float*)d_in[13];
    const float* alpha_gamma = (const float*)d_in[14];
    float* out = (float*)d_out;

    char* ws = (char*)d_ws;
    float*    ws_mean  = (float*)(ws + 0);            // 2048 f32
    float*    ws_rstd  = (float*)(ws + 8192);         // 2048 f32
    float*    ws_bs    = (float*)(ws + 16384);        // 256 f32
    float*    ws_bo    = (float*)(ws + 18432);        // 256 f32
    ushort_t* ws_Wt    = (ushort_t*)(ws + 20480);     // 9*512*640 bf16 = 5.9 MB
    ushort_t* ws_zp    = (ushort_t*)(ws + 6 * 1024 * 1024 - 65536);  // 32KB zero page
    ushort_t* ws_U     = (ushort_t*)(ws + 6 * 1024 * 1024);  // 8*128*128*640 bf16 = 167.8 MB

    (void)hipFuncSetAttribute((const void*)k_conv,
                              hipFuncAttributeMaxDynamicSharedMemorySize, 114688);

    k_prep<<<dim3(2048), dim3(256), 0, stream>>>(w_gamma, w_beta, w_sgamma, w_sbeta,
                                                 b_gamma, b_beta, b_sgamma, b_sbeta,
                                                 alpha_beta, alpha_gamma, ws_Wt, ws_bs, ws_bo,
                                                 (float*)ws_zp);
    k_stats<<<dim3(2048), dim3(256), 0, stream>>>(x, ws_mean, ws_rstd);
    k_buildU<<<dim3(1024), dim3(256), 0, stream>>>(segmap, style, w_shared, b_shared, ws_U);
    k_conv<<<dim3(1024), dim3(512), 114688, stream>>>(ws_U, ws_Wt, ws_zp, x, ws_mean, ws_rstd,
                                                      ws_bs, ws_bo, out);
}

// Round 12
// 924.025 us; speedup vs baseline: 2.7381x; 1.0368x over previous
//
#include <hip/hip_runtime.h>
#include <hip/hip_bf16.h>
#include <cstdint>

#define B_ 8
#define LABEL_NC 19
#define H_ 128
#define W_ 128
#define UC 640
#define EPS_ 1e-5f

typedef __attribute__((ext_vector_type(8))) short s8v;    // 8 bf16 (4 VGPR) MFMA frag
typedef __attribute__((ext_vector_type(4))) float f4v;    // MFMA acc
typedef __attribute__((ext_vector_type(4))) int i4v;      // 16B ld/st
typedef unsigned short ushort_t;

__device__ __forceinline__ ushort_t f2b(float f) {
    union { float f; uint32_t u; } a; a.f = f;
    uint32_t u = a.u;
    return (ushort_t)((u + 0x7FFFu + ((u >> 16) & 1u)) >> 16);  // RNE
}

__device__ __forceinline__ void gl2lds16(const ushort_t* g, ushort_t* l) {
    __builtin_amdgcn_global_load_lds(
        (const __attribute__((address_space(1))) unsigned int*)g,
        (__attribute__((address_space(3))) unsigned int*)l, 16, 0, 0);
}

// ---------------- fused aux kernel: buildU (1024 blocks) + stats (2048) + prep (2048) ----
// The three parts are data-independent; fusing lets VALU-bound buildU overlap BW-bound
// stats/prep across CUs and removes two full pipeline-drain gaps.
// Wt layout: [tap(9)][co(512)][ci(640)] bf16. co<256 scale, co>=256 offset.
__global__ void __launch_bounds__(256) k_aux(
    const float* __restrict__ x,
    const float* __restrict__ segmap, const float* __restrict__ style,
    const float* __restrict__ w_shared, const float* __restrict__ b_shared,
    const float* __restrict__ w_gamma, const float* __restrict__ w_beta,
    const float* __restrict__ w_sgamma, const float* __restrict__ w_sbeta,
    const float* __restrict__ b_gamma, const float* __restrict__ b_beta,
    const float* __restrict__ b_sgamma, const float* __restrict__ b_sbeta,
    const float* __restrict__ alpha_beta, const float* __restrict__ alpha_gamma,
    ushort_t* __restrict__ U, ushort_t* __restrict__ Wt,
    float* __restrict__ mean, float* __restrict__ rstd,
    float* __restrict__ bias_s, float* __restrict__ bias_o,
    float* __restrict__ zpage)
{
    __shared__ float seg[3][LABEL_NC][W_];   // used by buildU part only (29.2KB)
    int bid = blockIdx.x;

    if (bid < 1024) {
        // ================= buildU: U[b][h][w][640] bf16 (NHWC) =================
        int b = bid >> 7, h = bid & 127;
        const float* segb = segmap + (size_t)b * (LABEL_NC * H_ * W_);
        for (int idx = threadIdx.x; idx < 3 * LABEL_NC * W_; idx += 256) {
            int w = idx & 127;
            int l = (idx >> 7) % LABEL_NC;
            int rr = idx / (LABEL_NC * W_);
            int hh = h + rr - 1;
            seg[rr][l][w] = (hh >= 0 && hh < H_) ? segb[((size_t)l * H_ + hh) * W_ + w] : 0.f;
        }
        __syncthreads();

        int t = threadIdx.x;
        int w = t & 127;
        int grp = __builtin_amdgcn_readfirstlane(t >> 7);   // 0 or 1, wave-uniform
        ushort_t* Urow = U + (((size_t)(b * H_ + h)) * W_ + w) * UC;

        union pack16 { ushort_t u[16]; i4v v[2]; };

        for (int cb = 0; cb < 4; ++cb) {
            int co0 = grp * 64 + cb * 16;
            float acc[16];
            #pragma unroll
            for (int i = 0; i < 16; ++i) acc[i] = b_shared[co0 + i];
            for (int l = 0; l < LABEL_NC; ++l) {
                #pragma unroll
                for (int kh = 0; kh < 3; ++kh) {
                    float sm = (w > 0)   ? seg[kh][l][w - 1] : 0.f;
                    float s0 = seg[kh][l][w];
                    float sp = (w < 127) ? seg[kh][l][w + 1] : 0.f;
                    const float* wp = w_shared + ((size_t)co0 * LABEL_NC + l) * 9 + kh * 3;
                    #pragma unroll
                    for (int i = 0; i < 16; ++i) {
                        const float* wpi = wp + i * (LABEL_NC * 9);
                        acc[i] += sm * wpi[0] + s0 * wpi[1] + sp * wpi[2];
                    }
                }
            }
            pack16 pk;
            #pragma unroll
            for (int i = 0; i < 16; ++i) pk.u[i] = f2b(acc[i] > 0.f ? acc[i] : 0.f);
            *(i4v*)(Urow + co0) = pk.v[0];
            *(i4v*)(Urow + co0 + 8) = pk.v[1];
        }

        float segr[LABEL_NC];
        #pragma unroll
        for (int l = 0; l < LABEL_NC; ++l) segr[l] = seg[1][l][w];
        const float* styb = style + (size_t)b * (LABEL_NC * 512);
        for (int sb = 0; sb < 16; ++sb) {
            int s0 = grp * 256 + sb * 16;
            float acc[16];
            #pragma unroll
            for (int i = 0; i < 16; ++i) acc[i] = 0.f;
            for (int l = 0; l < LABEL_NC; ++l) {
                const float* sp = styb + l * 512 + s0;
                float sl = segr[l];
                #pragma unroll
                for (int i = 0; i < 16; ++i) acc[i] += sl * sp[i];
            }
            pack16 pk;
            #pragma unroll
            for (int i = 0; i < 16; ++i) pk.u[i] = f2b(acc[i]);
            *(i4v*)(Urow + 128 + s0) = pk.v[0];
            *(i4v*)(Urow + 128 + s0 + 8) = pk.v[1];
        }
    } else if (bid < 3072) {
        // ================= stats: per-(b,c) instance-norm =================
        int bc = bid - 1024;
        const float4* p = (const float4*)(x + (size_t)bc * (H_ * W_));
        float s = 0.f, s2 = 0.f;
        for (int i = threadIdx.x; i < H_ * W_ / 4; i += 256) {
            float4 v = p[i];
            s += v.x + v.y + v.z + v.w;
            s2 += v.x * v.x + v.y * v.y + v.z * v.z + v.w * v.w;
        }
        #pragma unroll
        for (int o = 32; o > 0; o >>= 1) { s += __shfl_xor(s, o); s2 += __shfl_xor(s2, o); }
        __shared__ float red[8];
        int wave = threadIdx.x >> 6, lane = threadIdx.x & 63;
        if (lane == 0) { red[wave] = s; red[wave + 4] = s2; }
        __syncthreads();
        if (threadIdx.x == 0) {
            float ts = red[0] + red[1] + red[2] + red[3];
            float t2 = red[4] + red[5] + red[6] + red[7];
            float m = ts * (1.f / 16384.f);
            float v = t2 * (1.f / 16384.f) - m * m;
            mean[bc] = m;
            rstd[bc] = rsqrtf(v + EPS_);
        }
    } else {
        // ================= prep: fold blend weights; biases; zero page =================
        float wb = 1.f / (1.f + __expf(-alpha_beta[0]));
        float wg = 1.f / (1.f + __expf(-alpha_gamma[0]));
        int gid = (bid - 3072) * 256 + threadIdx.x;
        if (gid < 256) bias_s[gid] = wg * b_sgamma[gid] + (1.f - wg) * b_gamma[gid];
        else if (gid < 512) bias_o[gid - 256] = wb * b_sbeta[gid - 256] + (1.f - wb) * b_beta[gid - 256];
        if (gid < 8192) zpage[gid] = 0.f;   // 32KB zero page

        const int total = 9 * 512 * 640;
        for (int idx = gid; idx < total; idx += 2048 * 256) {
            int tap = idx / (512 * 640);
            int r = idx - tap * (512 * 640);
            int co = r / 640, ci = r - co * 640;
            int kh = tap / 3, kw = tap - kh * 3;
            float v;
            if (co < 256) {
                if (ci < 128) v = (1.f - wg) * w_gamma[((co * 128 + ci) * 3 + kh) * 3 + kw];
                else          v = wg * w_sgamma[((co * 512 + (ci - 128)) * 3 + kh) * 3 + kw];
            } else {
                int c2 = co - 256;
                if (ci < 128) v = (1.f - wb) * w_beta[((c2 * 128 + ci) * 3 + kh) * 3 + kw];
                else          v = wb * w_sbeta[((c2 * 512 + (ci - 128)) * 3 + kh) * 3 + kw];
            }
            Wt[idx] = f2b(v);
        }
    }
}

// ---------------- kernel 3: main implicit-GEMM conv + fused epilogue (R6 body) ----------
// 512 threads (8 waves, 4wm x 2wn). M = 256 px (2 rows), N = 256 (128 scale + 128 offset).
// BK=32. LDS: A dbuf 2x32KB + B triple-buf 3x16KB = 112KB (reg-capped at 2 waves/SIMD:
// 128 arch + 128 acc = 256/wave).
// Deep pipeline: B(g) staged at g-2; raw s_barrier + counted vmcnt; A' staged at tap 7.
// LDS slot swizzle: phys_slot = data_slot ^ ((row>>1)&3) -> conflict-free (R6-verified).
#define BK 32

__global__ void __launch_bounds__(512, 1) k_conv(
    const ushort_t* __restrict__ U, const ushort_t* __restrict__ Wt,
    const ushort_t* __restrict__ zp,
    const float* __restrict__ x, const float* __restrict__ mean, const float* __restrict__ rstd,
    const float* __restrict__ bias_s, const float* __restrict__ bias_o,
    float* __restrict__ out)
{
    // bijective XCD-chunk swizzle (nwg=1024, 128 per XCD)
    int orig = blockIdx.x;
    int wg = (orig & 7) * 128 + (orig >> 3);
    int mtile = wg >> 1;
    int cohalf = wg & 1;
    int b = mtile >> 6;
    int h0 = (mtile & 63) << 1;

    extern __shared__ ushort_t smem[];
    // smem + ab*16384        : sA[2]  (each 4 rows x 128 px x 32 ci = 32KB)
    // smem + 32768 + bi*8192 : sB[3]  (each 256 ch x 32 ci = 16KB)

    int t = threadIdx.x;
    int wv = t >> 6, ln = t & 63;
    int wm = wv >> 1, wn = wv & 1;

    const ushort_t* Ub = U + (size_t)b * (H_ * W_ * UC);

    f4v acc[4][8] = {};   // [mi][ni]; ni<4 scale, ni>=4 offset (same channels)

    auto stage_A = [&](int ci0, int ab) {      // 4 loads/thread -> 32KB
        ushort_t* sAb = smem + ab * 16384;
        #pragma unroll
        for (int i = 0; i < 4; ++i) {
            int issue = wv * 4 + i;            // 32 issues of 1KB
            int hh = h0 - 1 + (issue >> 3);    // wave-uniform row
            int w = issue * 16 + (ln >> 2);
            int sl = (ln & 3) ^ ((w >> 1) & 3);    // inverse-swizzled source slot
            const ushort_t* src = (hh >= 0 && hh < H_)
                ? Ub + ((size_t)hh * W_ + (w & 127)) * UC + ci0 + (sl << 3)
                : zp + (size_t)ln * 8;
            gl2lds16(src, sAb + (size_t)issue * 512);
        }
    };
    auto stage_B = [&](int tapX, int ci0X, int bi) {   // 2 loads/thread -> 16KB
        ushort_t* base = smem + 32768 + bi * 8192;
        #pragma unroll
        for (int j = 0; j < 2; ++j) {
            int issue = wv * 2 + j;            // 16 issues of 1KB
            int c = issue * 16 + (ln >> 2);    // LDS row (0..255)
            int sl = (ln & 3) ^ ((c >> 1) & 3);
            int gq = (c >> 6) & 1;
            int cbase = ((c >> 7) << 6) + (c & 63);
            int co = gq * 256 + cohalf * 128 + cbase;
            const ushort_t* src = Wt + ((size_t)tapX * 512 + co) * UC + ci0X + (sl << 3);
            gl2lds16(src, base + (size_t)issue * 512);
        }
    };

    // ---- prologue: A(ch0), B(g=0), B(g=1) ----
    stage_A(0, 0);
    stage_B(0, 0, 0);
    stage_B(1, 0, 1);

    for (int ch = 0; ch < 20; ++ch) {
        int ci0 = ch * BK;
        ushort_t* sAb = smem + (ch & 1) * 16384;
        bool lastch = (ch == 19);
        #pragma unroll
        for (int tap = 0; tap < 9; ++tap) {
            const int dhp1 = tap / 3;            // compile-time after unroll
            const int dw = tap - dhp1 * 3 - 1;
            const int bi = tap % 3;              // 9 % 3 == 0 -> per-tap constant
            const int bi2 = (tap + 2) % 3;

            // counted waits: own B (and A at chunk entry) landed; newer loads in flight
            if (tap == 8) {
                if (lastch) { asm volatile("s_waitcnt vmcnt(0)" ::: "memory"); }
                else        { asm volatile("s_waitcnt vmcnt(6)" ::: "memory"); }
            } else          { asm volatile("s_waitcnt vmcnt(2)" ::: "memory"); }
            __builtin_amdgcn_s_barrier();

            // prefetch body g+2 (B), and next chunk's A at tap 7 (after B, order matters)
            if (tap < 7)        stage_B(tap + 2, ci0, bi2);
            else if (!lastch) {
                if (tap == 7) { stage_B(0, ci0 + BK, bi2); stage_A(ci0 + BK, (ch + 1) & 1); }
                else          stage_B(1, ci0 + BK, bi2);
            }

            // ---- compute: sA rows dhp1..dhp1+1 (dw shift), sB[bi] ----
            ushort_t* sBb = smem + 32768 + bi * 8192;
            int sd = ln >> 4;                 // 16B k-slot
            s8v af[4];
            #pragma unroll
            for (int mi = 0; mi < 4; ++mi) {
                int p = wm * 64 + mi * 16 + (ln & 15);
                int q = (p & 127) + dw;
                int qc = q < 0 ? 0 : (q > 127 ? 127 : q);
                int r = (p >> 7) + dhp1;
                s8v v = *(const s8v*)&sAb[(size_t)(((r * 128 + qc) << 2) + (sd ^ ((qc >> 1) & 3))) * 8];
                if (dw != 0 && (q < 0 || q > 127)) { s8v z = {}; v = z; }
                af[mi] = v;
            }
            s8v bf[8];
            #pragma unroll
            for (int ni = 0; ni < 8; ++ni) {
                int c = wn * 128 + (ni >> 2) * 64 + (ni & 3) * 16 + (ln & 15);
                bf[ni] = *(const s8v*)&sBb[(size_t)((c << 2) + (sd ^ ((c >> 1) & 3))) * 8];
            }
            __builtin_amdgcn_s_setprio(1);
            #pragma unroll
            for (int mi = 0; mi < 4; ++mi)
                #pragma unroll
                for (int ni = 0; ni < 8; ++ni)
                    acc[mi][ni] = __builtin_amdgcn_mfma_f32_16x16x32_bf16(
                        af[mi], bf[ni], acc[mi][ni], 0, 0, 0);
            __builtin_amdgcn_s_setprio(0);
        }
    }

    // ---- fused epilogue: out = (x-mu)*rstd*(scale+bs+1) + (offset+bo) ----
    int bc_base = b * 256;
    #pragma unroll
    for (int ni = 0; ni < 4; ++ni) {
        int chn = cohalf * 128 + wn * 64 + ni * 16 + (ln & 15);
        float bs = bias_s[chn] + 1.f;
        float bo = bias_o[chn];
        float mu = mean[bc_base + chn];
        float rs = rstd[bc_base + chn];
        #pragma unroll
        for (int mi = 0; mi < 4; ++mi) {
            #pragma unroll
            for (int r = 0; r < 4; ++r) {
                int p = wm * 64 + mi * 16 + ((ln >> 4) << 2) + r;
                int hh = h0 + (p >> 7);
                int ww = p & 127;
                size_t xi = (((size_t)(bc_base + chn)) * H_ + hh) * W_ + ww;
                float xn = (x[xi] - mu) * rs;
                out[xi] = xn * (acc[mi][ni][r] + bs) + (acc[mi][ni + 4][r] + bo);
            }
        }
    }
}

// ---------------- launcher ----------------
extern "C" void kernel_launch(void* const* d_in, const int* in_sizes, int n_in,
                              void* d_out, int out_size, void* d_ws, size_t ws_size,
                              hipStream_t stream)
{
    const float* x        = (const float*)d_in[0];
    const float* segmap   = (const float*)d_in[1];
    const float* style    = (const float*)d_in[2];
    const float* w_shared = (const float*)d_in[3];
    const float* b_shared = (const float*)d_in[4];
    const float* w_gamma  = (const float*)d_in[5];
    const float* b_gamma  = (const float*)d_in[6];
    const float* w_beta   = (const float*)d_in[7];
    const float* b_beta   = (const float*)d_in[8];
    const float* w_sgamma = (const float*)d_in[9];
    const float* b_sgamma = (const float*)d_in[10];
    const float* w_sbeta  = (const float*)d_in[11];
    const float* b_sbeta  = (const float*)d_in[12];
    const float* alpha_beta  = (const float*)d_in[13];
    const float* alpha_gamma = (const float*)d_in[14];
    float* out = (float*)d_out;

    char* ws = (char*)d_ws;
    float*    ws_mean  = (float*)(ws + 0);            // 2048 f32
    float*    ws_rstd  = (float*)(ws + 8192);         // 2048 f32
    float*    ws_bs    = (float*)(ws + 16384);        // 256 f32
    float*    ws_bo    = (float*)(ws + 18432);        // 256 f32
    ushort_t* ws_Wt    = (ushort_t*)(ws + 20480);     // 9*512*640 bf16 = 5.9 MB
    ushort_t* ws_zp    = (ushort_t*)(ws + 6 * 1024 * 1024 - 65536);  // 32KB zero page
    ushort_t* ws_U     = (ushort_t*)(ws + 6 * 1024 * 1024);  // 8*128*128*640 bf16 = 167.8 MB

    (void)hipFuncSetAttribute((const void*)k_conv,
                              hipFuncAttributeMaxDynamicSharedMemorySize, 114688);

    k_aux<<<dim3(5120), dim3(256), 0, stream>>>(x, segmap, style, w_shared, b_shared,
                                                w_gamma, w_beta, w_sgamma, w_sbeta,
                                                b_gamma, b_beta, b_sgamma, b_sbeta,
                                                alpha_beta, alpha_gamma,
                                                ws_U, ws_Wt, ws_mean, ws_rstd,
                                                ws_bs, ws_bo, (float*)ws_zp);
    k_conv<<<dim3(1024), dim3(512), 114688, stream>>>(ws_U, ws_Wt, ws_zp, x, ws_mean, ws_rstd,
                                                      ws_bs, ws_bo, out);
}